// Round 7
// baseline (7502.766 us; speedup 1.0000x reference)
//
#include <hip/hip_runtime.h>
#include <hip/hip_bf16.h>
#include <hip/hip_cooperative_groups.h>

namespace cg = cooperative_groups;

#define T_STEPS 4
#define N 4096
#define E 65536
#define XD 256
#define HD 256
#define ZD 64

typedef __hip_bfloat16 bf16;
typedef __attribute__((ext_vector_type(8))) short short8;
typedef __attribute__((ext_vector_type(4))) float f32x4;

__device__ __forceinline__ float b2f(bf16 v){ return __bfloat162float(v); }
__device__ __forceinline__ bf16 f2b(float v){ return __float2bfloat16(v); }
__device__ __forceinline__ short f2s(float v){ return __builtin_bit_cast(short, f2b(v)); }
__device__ __forceinline__ float bits2f(unsigned int s){ return __builtin_bit_cast(float, s << 16); }
__device__ __forceinline__ float splus(float x){ return (x > 20.f) ? x : log1pf(expf(x)); }
__device__ __forceinline__ float sigm(float x){ return 1.f/(1.f + expf(-x)); }

__device__ __forceinline__ float ldI(const void* p, size_t i, int f){
  return f ? ((const float*)p)[i] : b2f(((const bf16*)p)[i]);
}
__device__ __forceinline__ void stO(void* p, size_t i, float v, int f){
  if (f) ((float*)p)[i] = v; else ((bf16*)p)[i] = f2b(v);
}
__device__ __forceinline__ void ld8b(const bf16* p, float v[8]){
  uint4 u = *(const uint4*)p;
  v[0]=bits2f(u.x & 0xffffu); v[1]=bits2f(u.x >> 16);
  v[2]=bits2f(u.y & 0xffffu); v[3]=bits2f(u.y >> 16);
  v[4]=bits2f(u.z & 0xffffu); v[5]=bits2f(u.z >> 16);
  v[6]=bits2f(u.w & 0xffffu); v[7]=bits2f(u.w >> 16);
}
__device__ __forceinline__ unsigned int pack2(float a, float b){
  return (unsigned int)(unsigned short)__builtin_bit_cast(unsigned short, f2b(a))
       | ((unsigned int)(unsigned short)__builtin_bit_cast(unsigned short, f2b(b)) << 16);
}

union SMem {
  struct { short As[64*40]; short Wt[64*40]; } g;        // 10 KB (GEMM)
  struct { float ziT[64*68]; float zjT[64*68]; } d;      // 34.8 KB (dec_nll)
  int sh[256];
  float red[256];
};

struct KP {
  const void *x, *adj, *eps, *h0;
  const int* ei;
  const void *phi_x_w, *phi_x_b, *phi_z_w, *phi_z_b;
  const void *enc_w, *enc_b, *enc_mean_w, *enc_mean_b, *enc_std_w, *enc_std_b;
  const void *prior_w, *prior_b, *prior_mean_w, *prior_mean_b, *prior_std_w, *prior_std_b;
  const void *gxz, *ghz, *gxr, *ghr, *gxh, *ghh;
  void* out;
  float* scal; int* dflag; float* dinv; int* offs; int* srcs; float* enorm; int* deg;
  float* h_prev; bf16* h_bf; bf16* phiXa; bf16* Tb1; bf16* Tb2;
  float* zbuf; float* ms; float* z_g; bf16* Gs1; bf16* Gsx; bf16* Gms; bf16* Gh2;
  int phase;   // -1 = run all phases with grid sync (cooperative); else run one phase
};

#define OUT_EM ((size_t)2)
#define OUT_PM ((size_t)(2 + (size_t)T_STEPS*N*ZD))
#define OUT_H  ((size_t)(2 + (size_t)2*T_STEPS*N*ZD))

// ---------------- MFMA 64x64 tile: C = [A1|A2] @ W(+bias)(+relu), bf16 out ----------------
// amode: 0 = f32 ws, 1 = input (f dispatch), 2 = bf16 ws
__device__ void mfma_tile(SMem& sm, int tid, int f,
    const void* A1, int am1, int lda1, const void* A2, int am2, int lda2,
    int K1, int K, const void* W, int ldw, int wcol,
    const void* bias, int act, bf16* C, int ldc, int row0, int ccol0){
  int ar = tid >> 2, akk = (tid & 3)*8;
  int wk = tid >> 3, wn = (tid & 7)*8;
  int wave = tid >> 6, lane = tid & 63, m = lane & 15, kq = lane >> 4;
  f32x4 acc[4] = {};
  for (int k0 = 0; k0 < K; k0 += 32){
    const void* A; int am, lda, kb;
    if (k0 < K1){ A = A1; am = am1; lda = lda1; kb = k0; }
    else        { A = A2; am = am2; lda = lda2; kb = k0 - K1; }
    size_t aidx = (size_t)(row0 + ar)*lda + kb + akk;
    short8 av;
    if (am == 2 || (am == 1 && f == 0)){
      av = *(const short8*)((const short*)A + aidx);
    } else {
      const float* Af = (const float*)A;
      float4 u0 = *(const float4*)(Af + aidx);
      float4 u1 = *(const float4*)(Af + aidx + 4);
      av[0]=f2s(u0.x); av[1]=f2s(u0.y); av[2]=f2s(u0.z); av[3]=f2s(u0.w);
      av[4]=f2s(u1.x); av[5]=f2s(u1.y); av[6]=f2s(u1.z); av[7]=f2s(u1.w);
    }
    *(short8*)&sm.g.As[ar*40 + akk] = av;
    size_t wi = (size_t)(k0 + wk)*ldw + wcol + wn;
    short wv[8];
    if (f == 0){
      short8 t8 = *(const short8*)((const short*)W + wi);
      #pragma unroll
      for (int j = 0; j < 8; j++) wv[j] = t8[j];
    } else {
      const float* Wf = (const float*)W;
      float4 u0 = *(const float4*)(Wf + wi);
      float4 u1 = *(const float4*)(Wf + wi + 4);
      wv[0]=f2s(u0.x); wv[1]=f2s(u0.y); wv[2]=f2s(u0.z); wv[3]=f2s(u0.w);
      wv[4]=f2s(u1.x); wv[5]=f2s(u1.y); wv[6]=f2s(u1.z); wv[7]=f2s(u1.w);
    }
    #pragma unroll
    for (int j = 0; j < 8; j++) sm.g.Wt[(wn + j)*40 + wk] = wv[j];
    __syncthreads();
    short8 afr = *(const short8*)&sm.g.As[(wave*16 + m)*40 + kq*8];
    #pragma unroll
    for (int t4 = 0; t4 < 4; t4++){
      short8 bfr = *(const short8*)&sm.g.Wt[(t4*16 + m)*40 + kq*8];
      acc[t4] = __builtin_amdgcn_mfma_f32_16x16x32_bf16(afr, bfr, acc[t4], 0, 0, 0);
    }
    __syncthreads();
  }
  #pragma unroll
  for (int t4 = 0; t4 < 4; t4++){
    int c = ccol0 + t4*16 + m;
    float bv = bias ? ldI(bias, wcol + t4*16 + m, f) : 0.f;
    #pragma unroll
    for (int reg = 0; reg < 4; reg++){
      int r = row0 + wave*16 + kq*4 + reg;
      float v = acc[t4][reg] + bv;
      if (act == 1) v = fmaxf(v, 0.f);
      C[(size_t)r*ldc + c] = f2b(v);
    }
  }
}

// ---------------- dec_nll: one 64x64 tile, accumulates ts/P/Q ----------------
__device__ void dec_tile(const KP& p, SMem& sm, int tid, int t, int u, int f){
  __syncthreads();
  int i0 = (u >> 6)*64, j0 = (u & 63)*64;
  size_t aoff = (size_t)t*N*N;
  #pragma unroll
  for (int k = 0; k < 16; k++){
    int ii = tid + k*256; int r = ii >> 6, d = ii & 63;
    sm.d.ziT[d*68 + r] = p.zbuf[(size_t)(i0+r)*ZD + d];
    sm.d.zjT[d*68 + r] = p.zbuf[(size_t)(j0+r)*ZD + d];
  }
  __syncthreads();
  int tx = tid & 15, ty = tid >> 4;
  float acc[4][4] = {};
  #pragma unroll 8
  for (int d = 0; d < 64; d++){
    float4 ra = *(const float4*)&sm.d.ziT[d*68 + ty*4];
    float4 rb = *(const float4*)&sm.d.zjT[d*68 + tx*4];
    acc[0][0] += ra.x*rb.x; acc[0][1] += ra.x*rb.y; acc[0][2] += ra.x*rb.z; acc[0][3] += ra.x*rb.w;
    acc[1][0] += ra.y*rb.x; acc[1][1] += ra.y*rb.y; acc[1][2] += ra.y*rb.z; acc[1][3] += ra.y*rb.w;
    acc[2][0] += ra.z*rb.x; acc[2][1] += ra.z*rb.y; acc[2][2] += ra.z*rb.z; acc[2][3] += ra.z*rb.w;
    acc[3][0] += ra.w*rb.x; acc[3][1] += ra.w*rb.y; acc[3][2] += ra.w*rb.z; acc[3][3] += ra.w*rb.w;
  }
  float lts = 0.f, lP = 0.f, lQ = 0.f;
  #pragma unroll
  for (int pp = 0; pp < 4; pp++){
    int i = i0 + ty*4 + pp;
    size_t rowoff = aoff + (size_t)i*N + j0 + tx*4;
    float av4[4];
    if (f){
      float4 v = *(const float4*)((const float*)p.adj + rowoff);
      av4[0] = v.x; av4[1] = v.y; av4[2] = v.z; av4[3] = v.w;
    } else {
      const bf16* pb = (const bf16*)p.adj + rowoff;
      av4[0] = b2f(pb[0]); av4[1] = b2f(pb[1]); av4[2] = b2f(pb[2]); av4[3] = b2f(pb[3]);
    }
    #pragma unroll
    for (int q = 0; q < 4; q++){
      float dec = sigm(acc[pp][q]);
      float av = av4[q];
      lts += av;
      lQ += (1.f - av)*log1pf(expf(dec));
      if (av != 0.f) lP += av*log1pf(expf(-dec));
    }
  }
  __syncthreads();
  sm.d.ziT[tid] = lts; __syncthreads();
  for (int o = 128; o > 0; o >>= 1){ if (tid < o) sm.d.ziT[tid] += sm.d.ziT[tid+o]; __syncthreads(); }
  if (tid == 0) atomicAdd(p.scal + 8 + t, sm.d.ziT[0]);
  __syncthreads();
  sm.d.ziT[tid] = lP; __syncthreads();
  for (int o = 128; o > 0; o >>= 1){ if (tid < o) sm.d.ziT[tid] += sm.d.ziT[tid+o]; __syncthreads(); }
  if (tid == 0) atomicAdd(p.scal + 12 + t, sm.d.ziT[0]);
  __syncthreads();
  sm.d.ziT[tid] = lQ; __syncthreads();
  for (int o = 128; o > 0; o >>= 1){ if (tid < o) sm.d.ziT[tid] += sm.d.ziT[tid+o]; __syncthreads(); }
  if (tid == 0) atomicAdd(p.scal + 16 + t, sm.d.ziT[0]);
}

// ---------------- phase runner ----------------
__device__ void run_phase(const KP& p, int ph, SMem& sm){
  int gb = blockIdx.x, tid = threadIdx.x;
  int f = (ph >= 2) ? *p.dflag : 0;

  if (ph == 0){                                   // zero scal/deg, detect dtype
    if (gb == 0){ if (tid < 64) p.scal[tid] = 0.f; }
    else if (gb == 1){
      if (tid == 0){
        const unsigned short* u = (const unsigned short*)p.x;
        int big = 0;
        for (int i = 0; i < 256; i++){ int e = (u[i] >> 7) & 0xFF; if (e >= 134) big++; }
        *p.dflag = (big > 16) ? 1 : 0;
      }
    } else if (gb < 66){
      p.deg[(gb-2)*256 + tid] = 0;                // 64*256 = T*N
    }
    return;
  }
  if (ph == 1){                                   // count degrees (1024 blocks exact)
    int idx = gb*256 + tid;
    int t = idx >> 16, e = idx & (E-1);
    int dst = p.ei[(size_t)t*2*E + E + e] & (N-1);
    atomicAdd(&p.deg[t*N + dst], 1);
    return;
  }
  if (ph == 2){                                   // scan (blocks 0-3) + h0 copy (rest)
    if (gb < 4){
      int t = gb;
      const int* dg = p.deg + t*N;
      int* of = p.offs + t*(N+1);
      int base = tid*16;
      int loc[16]; int s = 0;
      #pragma unroll
      for (int i = 0; i < 16; i++){ loc[i] = s; s += dg[base+i]; }
      sm.sh[tid] = s;
      __syncthreads();
      for (int o = 1; o < 256; o <<= 1){
        int v = (tid >= o) ? sm.sh[tid-o] : 0;
        __syncthreads();
        sm.sh[tid] += v;
        __syncthreads();
      }
      int pre = (tid == 0) ? 0 : sm.sh[tid-1];
      #pragma unroll
      for (int i = 0; i < 16; i++) of[base+i] = pre + loc[i];
      if (tid == 255) of[N] = sm.sh[255];
      #pragma unroll
      for (int i = 0; i < 16; i++) p.dinv[t*N + base + i] = rsqrtf(1.f + (float)dg[base+i]);
    } else {
      for (int idx = (gb-4)*256 + tid; idx < N*HD; idx += 1020*256){
        float v = ldI(p.h0, idx, f);
        p.h_prev[idx] = v; p.h_bf[idx] = f2b(v);
      }
    }
    return;
  }
  if (ph == 3){                                   // cursor init (0-63) + phi_x GEMM (64+)
    if (gb < 64){
      int idx = gb*256 + tid;
      int t = idx >> 12, n = idx & (N-1);
      p.deg[idx] = p.offs[t*(N+1) + n];           // deg reused as cursor
    } else {
      for (int u = gb - 64; u < 1024; u += 960){
        int colblk = u & 3, rowblk = u >> 2;
        mfma_tile(sm, tid, f, p.x, 1, XD, nullptr, 0, 0, XD, XD,
                  p.phi_x_w, HD, colblk*64, p.phi_x_b, 1,
                  p.phiXa, HD, rowblk*64, colblk*64);
      }
    }
    return;
  }
  if (ph == 4){                                   // scatter (1024 exact)
    int idx = gb*256 + tid;
    int t = idx >> 16, e = idx & (E-1);
    int s = p.ei[(size_t)t*2*E + e] & (N-1);
    int d = p.ei[(size_t)t*2*E + E + e] & (N-1);
    int pos = atomicAdd(&p.deg[t*N + d], 1);
    if (pos >= 0 && pos < E){
      p.srcs[(size_t)t*E + pos] = s;
      p.enorm[(size_t)t*E + pos] = p.dinv[t*N + s] * p.dinv[t*N + d];
    }
    return;
  }
  if (ph == 45){                                  // finalize
    if (gb == 0 && tid == 0){
      const float NNf = 16777216.f;
      float nll = 0.f;
      for (int t = 0; t < T_STEPS; t++){
        float ts = p.scal[8+t], P = p.scal[12+t], Q = p.scal[16+t];
        float posw = (NNf - ts)/ts;
        nll += (posw*P + Q) * 0.5f/(NNf - ts);
      }
      stO(p.out, 0, p.scal[4], f);
      stO(p.out, 1, nll, f);
    }
    return;
  }

  // ---- per-timestep phases ----
  int t = (ph - 5) / 10, sub = (ph - 5) % 10;
  const bf16* phiX = p.phiXa + (size_t)t*N*HD;
  const int* offs_t = p.offs + t*(N+1);
  const int* srcs_t = p.srcs + (size_t)t*E;
  const float* en_t = p.enorm + (size_t)t*E;
  const float* dv_t = p.dinv + t*N;

  if (sub == 0){                                  // group1 GEMM: [enc|prior|hz|hr] M=1024
    int colblk = gb & 15, rowblk = gb >> 4;
    int grp = colblk >> 2, c4 = colblk & 3;
    if (grp == 0)
      mfma_tile(sm, tid, f, phiX, 2, HD, p.h_bf, 2, HD, 256, 512,
                p.enc_w, HD, c4*64, nullptr, 0, p.Gs1, 1024, rowblk*64, colblk*64);
    else if (grp == 1)
      mfma_tile(sm, tid, f, p.h_bf, 2, HD, nullptr, 0, 0, 256, 256,
                p.prior_w, HD, c4*64, p.prior_b, 1, p.Gs1, 1024, rowblk*64, colblk*64);
    else if (grp == 2)
      mfma_tile(sm, tid, f, p.h_bf, 2, HD, nullptr, 0, 0, 256, 256,
                p.ghz, HD, c4*64, nullptr, 0, p.Gs1, 1024, rowblk*64, colblk*64);
    else
      mfma_tile(sm, tid, f, p.h_bf, 2, HD, nullptr, 0, 0, 256, 256,
                p.ghr, HD, c4*64, nullptr, 0, p.Gs1, 1024, rowblk*64, colblk*64);
    return;
  }
  if (sub == 1){                                  // enc agg (0-511) + prior-ms GEMM (512-639)
    if (gb < 512){
      int g8 = tid >> 5, l = tid & 31;
      int n = gb*8 + g8, c = l*8;
      int e0 = offs_t[n], e1 = offs_t[n+1];
      float d2 = dv_t[n]*dv_t[n];
      float acc[8], v[8];
      ld8b(p.Gs1 + (size_t)n*1024 + c, v);
      #pragma unroll
      for (int j = 0; j < 8; j++) acc[j] = d2 * v[j];
      for (int e = e0; e < e1; e++){
        int s = srcs_t[e] & (N-1);
        float nm = en_t[e];
        ld8b(p.Gs1 + (size_t)s*1024 + c, v);
        #pragma unroll
        for (int j = 0; j < 8; j++) acc[j] += nm * v[j];
      }
      #pragma unroll
      for (int j = 0; j < 8; j++) acc[j] = fmaxf(acc[j] + ldI(p.enc_b, c + j, f), 0.f);
      uint4 o; o.x = pack2(acc[0],acc[1]); o.y = pack2(acc[2],acc[3]);
      o.z = pack2(acc[4],acc[5]); o.w = pack2(acc[6],acc[7]);
      *(uint4*)(p.Tb1 + (size_t)n*HD + c) = o;
    } else if (gb < 640){
      int u = gb - 512;
      int colblk = u & 1, rowblk = u >> 1;
      mfma_tile(sm, tid, f, p.Gs1 + 256, 2, 1024, nullptr, 0, 0, 256, 256,
                colblk ? p.prior_std_w : p.prior_mean_w, ZD, 0,
                colblk ? p.prior_std_b : p.prior_mean_b, 0,
                p.Gms, 256, rowblk*64, 128 + colblk*64);
    }
    return;
  }
  if (sub == 2){                                  // enc-ms GEMM (128 tiles)
    if (gb < 128){
      int colblk = gb & 1, rowblk = gb >> 1;
      mfma_tile(sm, tid, f, p.Tb1, 2, HD, nullptr, 0, 0, 256, 256,
                colblk ? p.enc_std_w : p.enc_mean_w, ZD, 0, nullptr, 0,
                p.Gms, 256, rowblk*64, colblk*64);
    }
    return;
  }
  if (sub == 3){                                  // ms agg (256 blocks)
    if (gb < 256){
      int g16 = tid >> 4, l = tid & 15;
      int n = gb*16 + g16, c = l*8;
      int e0 = offs_t[n], e1 = offs_t[n+1];
      float d2 = dv_t[n]*dv_t[n];
      float acc[8], v[8];
      ld8b(p.Gms + (size_t)n*256 + c, v);
      #pragma unroll
      for (int j = 0; j < 8; j++) acc[j] = d2 * v[j];
      for (int e = e0; e < e1; e++){
        int s = srcs_t[e] & (N-1);
        float nm = en_t[e];
        ld8b(p.Gms + (size_t)s*256 + c, v);
        #pragma unroll
        for (int j = 0; j < 8; j++) acc[j] += nm * v[j];
      }
      size_t base = (size_t)n*128 + c;
      float4 o0 = {acc[0],acc[1],acc[2],acc[3]}, o1 = {acc[4],acc[5],acc[6],acc[7]};
      *(float4*)(p.ms + base) = o0;
      *(float4*)(p.ms + base + 4) = o1;
    }
    return;
  }
  if (sub == 4){                                  // post: z, out_em/out_pm, kld (1024 exact)
    int idx = gb*256 + tid;
    int n = idx >> 6, d = idx & 63;
    float mean = p.ms[n*128 + d] + ldI(p.enc_mean_b, d, f);
    float sd = splus(p.ms[n*128 + 64 + d] + ldI(p.enc_std_b, d, f));
    p.zbuf[idx] = ldI(p.eps, (size_t)t*N*ZD + idx, f) * sd + mean;
    stO(p.out, OUT_EM + (size_t)t*N*ZD + idx, mean, f);
    float pm = b2f(p.Gms[n*256 + 128 + d]);
    float ps = splus(b2f(p.Gms[n*256 + 192 + d]));
    stO(p.out, OUT_PM + (size_t)t*N*ZD + idx, pm, f);
    float s1 = sd + 1e-10f, s2 = ps + 1e-10f;
    float dm = mean - pm;
    float el = 2.f*(logf(s2) - logf(s1)) - (s1*s1 + dm*dm)/(s2*s2) + 1.f;
    sm.red[tid] = el; __syncthreads();
    for (int o = 128; o > 0; o >>= 1){ if (tid < o) sm.red[tid] += sm.red[tid+o]; __syncthreads(); }
    if (tid == 0) atomicAdd(p.scal + 4, sm.red[0] * (0.5f/((float)N*(float)ZD)));
    return;
  }
  if (sub == 5){                                  // phi_z GEMM (0-255) + dec tiles (256-1023)
    if (gb < 256){
      int colblk = gb & 3, rowblk = gb >> 2;
      mfma_tile(sm, tid, f, p.zbuf, 0, ZD, nullptr, 0, 0, ZD, ZD,
                p.phi_z_w, HD, colblk*64, p.phi_z_b, 1, p.Tb2, HD, rowblk*64, colblk*64);
    } else {
      int base = (gb - 256)*4;
      for (int i = 0; i < 4; i++) dec_tile(p, sm, tid, t, base + i, f);
    }
    return;
  }
  if (sub == 6){                                  // gru-x GEMM (0-767) + dec tiles (768-1023)
    if (gb < 768){
      int colblk = gb % 12, rowblk = gb / 12;
      int grp = colblk >> 2, c4 = colblk & 3;
      const void* W = (grp == 0) ? p.gxz : ((grp == 1) ? p.gxr : p.gxh);
      mfma_tile(sm, tid, f, phiX, 2, HD, p.Tb2, 2, HD, 256, 512,
                W, HD, c4*64, nullptr, 0, p.Gsx, 768, rowblk*64, colblk*64);
    } else {
      int base = 3072 + (gb - 768)*4;
      for (int i = 0; i < 4; i++) dec_tile(p, sm, tid, t, base + i, f);
    }
    return;
  }
  if (sub == 7){                                  // z+r gate agg (1024 exact)
    int g4 = tid >> 6, lane = tid & 63;
    int n = gb*4 + g4, c = lane*8;
    int e0 = offs_t[n], e1 = offs_t[n+1];
    float d2 = dv_t[n]*dv_t[n];
    float acc[8], v1[8], v2[8];
    ld8b(p.Gsx + (size_t)n*768 + c, v1);
    ld8b(p.Gs1 + 512 + (size_t)n*1024 + c, v2);
    #pragma unroll
    for (int j = 0; j < 8; j++) acc[j] = d2 * (v1[j] + v2[j]);
    for (int e = e0; e < e1; e++){
      int s = srcs_t[e] & (N-1);
      float nm = en_t[e];
      ld8b(p.Gsx + (size_t)s*768 + c, v1);
      ld8b(p.Gs1 + 512 + (size_t)s*1024 + c, v2);
      #pragma unroll
      for (int j = 0; j < 8; j++) acc[j] += nm * (v1[j] + v2[j]);
    }
    if (c < 256){
      size_t base = (size_t)n*HD + c;
      float4 o0, o1;
      o0.x = sigm(acc[0]); o0.y = sigm(acc[1]); o0.z = sigm(acc[2]); o0.w = sigm(acc[3]);
      o1.x = sigm(acc[4]); o1.y = sigm(acc[5]); o1.z = sigm(acc[6]); o1.w = sigm(acc[7]);
      *(float4*)(p.z_g + base) = o0;
      *(float4*)(p.z_g + base + 4) = o1;
    } else {
      size_t base = (size_t)n*HD + (c - 256);
      float r[8];
      #pragma unroll
      for (int j = 0; j < 8; j++) r[j] = sigm(acc[j]) * p.h_prev[base+j];
      uint4 o; o.x = pack2(r[0],r[1]); o.y = pack2(r[2],r[3]);
      o.z = pack2(r[4],r[5]); o.w = pack2(r[6],r[7]);
      *(uint4*)(p.Tb1 + base) = o;
    }
    return;
  }
  if (sub == 8){                                  // hh GEMM (256 tiles)
    if (gb < 256){
      int colblk = gb & 3, rowblk = gb >> 2;
      mfma_tile(sm, tid, f, p.Tb1, 2, HD, nullptr, 0, 0, 256, 256,
                p.ghh, HD, colblk*64, nullptr, 0, p.Gh2, 256, rowblk*64, colblk*64);
    }
    return;
  }
  // sub == 9: h update agg (0-511)
  if (gb < 512){
    int g8 = tid >> 5, l = tid & 31;
    int n = gb*8 + g8, c = l*8;
    int e0 = offs_t[n], e1 = offs_t[n+1];
    float d2 = dv_t[n]*dv_t[n];
    float acc[8], v1[8], v2[8];
    ld8b(p.Gsx + 512 + (size_t)n*768 + c, v1);
    ld8b(p.Gh2 + (size_t)n*256 + c, v2);
    #pragma unroll
    for (int j = 0; j < 8; j++) acc[j] = d2 * (v1[j] + v2[j]);
    for (int e = e0; e < e1; e++){
      int s = srcs_t[e] & (N-1);
      float nm = en_t[e];
      ld8b(p.Gsx + 512 + (size_t)s*768 + c, v1);
      ld8b(p.Gh2 + (size_t)s*256 + c, v2);
      #pragma unroll
      for (int j = 0; j < 8; j++) acc[j] += nm * (v1[j] + v2[j]);
    }
    size_t base = (size_t)n*HD + c;
    #pragma unroll
    for (int j = 0; j < 8; j++){
      float z = p.z_g[base+j];
      float hv = p.h_prev[base+j];
      float nv = z*hv + (1.f - z)*tanhf(acc[j]);
      p.h_prev[base+j] = nv;
      p.h_bf[base+j] = f2b(nv);
      if (t == T_STEPS-1) stO(p.out, OUT_H + base + j, nv, f);
    }
  }
}

// ---------------- mega kernel ----------------
__global__ __launch_bounds__(256, 4) void mega_k(KP p){
  __shared__ SMem sm;
  if (p.phase >= 0){ run_phase(p, p.phase, sm); return; }
  cg::grid_group grid = cg::this_grid();
  for (int ph = 0; ph < 46; ph++){
    run_phase(p, ph, sm);
    grid.sync();
  }
}

// ---------------- host ----------------
extern "C" void kernel_launch(void* const* d_in, const int* in_sizes, int n_in,
                              void* d_out, int out_size, void* d_ws, size_t ws_size,
                              hipStream_t stream){
  KP P;
  P.x = d_in[0];  P.ei = (const int*)d_in[1];  P.adj = d_in[2];  P.eps = d_in[3];  P.h0 = d_in[4];
  P.phi_x_w = d_in[5];  P.phi_x_b = d_in[6];  P.phi_z_w = d_in[7];  P.phi_z_b = d_in[8];
  P.enc_w = d_in[9];  P.enc_b = d_in[10];
  P.enc_mean_w = d_in[11];  P.enc_mean_b = d_in[12];
  P.enc_std_w = d_in[13];   P.enc_std_b = d_in[14];
  P.prior_w = d_in[15];  P.prior_b = d_in[16];
  P.prior_mean_w = d_in[17];  P.prior_mean_b = d_in[18];
  P.prior_std_w = d_in[19];   P.prior_std_b = d_in[20];
  P.gxz = d_in[21];  P.ghz = d_in[22];  P.gxr = d_in[23];
  P.ghr = d_in[24];  P.gxh = d_in[25];  P.ghh = d_in[26];
  P.out = d_out;

  char* wp = (char*)d_ws;
  auto alloc = [&](size_t bytes){ void* q = (void*)wp; wp += (bytes + 255) & ~(size_t)255; return q; };
  P.scal  = (float*)alloc(64*sizeof(float));
  P.dflag = (int*)  alloc(256);
  P.dinv  = (float*)alloc((size_t)T_STEPS*N*4);
  P.offs  = (int*)  alloc((size_t)T_STEPS*(N+1)*4);
  P.srcs  = (int*)  alloc((size_t)T_STEPS*E*4);
  P.enorm = (float*)alloc((size_t)T_STEPS*E*4);
  P.deg   = (int*)  alloc((size_t)T_STEPS*N*4);
  P.h_prev= (float*)alloc((size_t)N*HD*4);
  P.h_bf  = (bf16*) alloc((size_t)N*HD*2);
  P.phiXa = (bf16*) alloc((size_t)T_STEPS*N*HD*2);
  P.Tb1   = (bf16*) alloc((size_t)N*HD*2);
  P.Tb2   = (bf16*) alloc((size_t)N*HD*2);
  P.zbuf  = (float*)alloc((size_t)N*ZD*4);
  P.ms    = (float*)alloc((size_t)N*128*4);
  P.z_g   = (float*)alloc((size_t)N*HD*4);
  P.Gs1   = (bf16*) alloc((size_t)N*1024*2);
  P.Gsx   = (bf16*) alloc((size_t)N*768*2);
  P.Gms   = (bf16*) alloc((size_t)N*256*2);
  P.Gh2   = (bf16*) alloc((size_t)N*256*2);

  P.phase = -1;
  void* args[] = { &P };
  hipError_t err = hipLaunchCooperativeKernel((const void*)mega_k, dim3(1024), dim3(256),
                                              args, 0, stream);
  if (err != hipSuccess){
    (void)hipGetLastError();                      // clear; fall back to per-phase launches
    for (int ph = 0; ph < 46; ph++){
      P.phase = ph;
      mega_k<<<dim3(1024), dim3(256), 0, stream>>>(P);
    }
  }
}

// Round 8
// 1868.413 us; speedup vs baseline: 4.0156x; 4.0156x over previous
//
#include <hip/hip_runtime.h>
#include <hip/hip_bf16.h>

#define T_STEPS 4
#define N 4096
#define E 65536
#define XD 256
#define HD 256
#define ZD 64

typedef __hip_bfloat16 bf16;
typedef __attribute__((ext_vector_type(8))) short short8;
typedef __attribute__((ext_vector_type(4))) float f32x4;

__device__ __forceinline__ float b2f(bf16 v){ return __bfloat162float(v); }
__device__ __forceinline__ bf16 f2b(float v){ return __float2bfloat16(v); }
__device__ __forceinline__ short f2s(float v){ return __builtin_bit_cast(short, f2b(v)); }
__device__ __forceinline__ float bits2f(unsigned int s){ return __builtin_bit_cast(float, s << 16); }
__device__ __forceinline__ float splus(float x){ return (x > 20.f) ? x : log1pf(expf(x)); }
__device__ __forceinline__ float sigm(float x){ return 1.f/(1.f + expf(-x)); }

__device__ __forceinline__ float ldI(const void* p, size_t i, int f){
  return f ? ((const float*)p)[i] : b2f(((const bf16*)p)[i]);
}
__device__ __forceinline__ void stO(void* p, size_t i, float v, int f){
  if (f) ((float*)p)[i] = v; else ((bf16*)p)[i] = f2b(v);
}
__device__ __forceinline__ void ld8b(const bf16* p, float v[8]){
  uint4 u = *(const uint4*)p;
  v[0]=bits2f(u.x & 0xffffu); v[1]=bits2f(u.x >> 16);
  v[2]=bits2f(u.y & 0xffffu); v[3]=bits2f(u.y >> 16);
  v[4]=bits2f(u.z & 0xffffu); v[5]=bits2f(u.z >> 16);
  v[6]=bits2f(u.w & 0xffffu); v[7]=bits2f(u.w >> 16);
}
__device__ __forceinline__ unsigned int pack2(float a, float b){
  return (unsigned int)(unsigned short)__builtin_bit_cast(unsigned short, f2b(a))
       | ((unsigned int)(unsigned short)__builtin_bit_cast(unsigned short, f2b(b)) << 16);
}

union SMem {
  struct { short As[64*40]; short Wt[64*40]; } g;   // 10.2 KB (GEMM)
  struct { short Zi[64*72]; short Zj[64*72]; } z;   // 18.4 KB (dec MFMA)
  struct { float msh[16*128]; } m;                  // 8 KB (ms-agg+post)
  int sh[256];
  float red[256];
};

struct KP {
  const void *x, *adj, *eps, *h0;
  const int* ei;
  const void *phi_x_w, *phi_x_b, *phi_z_w, *phi_z_b;
  const void *enc_w, *enc_b, *enc_mean_w, *enc_mean_b, *enc_std_w, *enc_std_b;
  const void *prior_w, *prior_b, *prior_mean_w, *prior_mean_b, *prior_std_w, *prior_std_b;
  const void *gxz, *ghz, *gxr, *ghr, *gxh, *ghh;
  void* out;
  float* scal; int* dflag; float* dinv; int* offs; int* srcs; float* enorm; int* deg;
  float* h_prev; bf16* h_bf; bf16* phiXa; bf16* Tb1; bf16* Tb2;
  bf16* zbf; float* z_g; bf16* Gs1; bf16* Gsx; bf16* Gms; bf16* Gh2;
};

#define OUT_EM ((size_t)2)
#define OUT_PM ((size_t)(2 + (size_t)T_STEPS*N*ZD))
#define OUT_H  ((size_t)(2 + (size_t)2*T_STEPS*N*ZD))

// ---------------- MFMA 64x64 tile: C = [A1|A2] @ W(+bias)(+relu), bf16 out ----------------
// Wt LDS layout is XOR-chunk-swizzled (chunk ^= (row>>3)&3) to break 8-way write conflicts.
__device__ void mfma_tile(SMem& sm, int tid, int f,
    const void* A1, int am1, int lda1, const void* A2, int am2, int lda2,
    int K1, int K, const void* W, int ldw, int wcol,
    const void* bias, int act, bf16* C, int ldc, int row0, int ccol0){
  int ar = tid >> 2, akk = (tid & 3)*8;
  int wk = tid >> 3, wn = (tid & 7)*8;
  int wave = tid >> 6, lane = tid & 63, m = lane & 15, kq = lane >> 4;
  f32x4 acc[4] = {};
  for (int k0 = 0; k0 < K; k0 += 32){
    const void* A; int am, lda, kb;
    if (k0 < K1){ A = A1; am = am1; lda = lda1; kb = k0; }
    else        { A = A2; am = am2; lda = lda2; kb = k0 - K1; }
    size_t aidx = (size_t)(row0 + ar)*lda + kb + akk;
    short8 av;
    if (am == 2 || (am == 1 && f == 0)){
      av = *(const short8*)((const short*)A + aidx);
    } else {
      const float* Af = (const float*)A;
      float4 u0 = *(const float4*)(Af + aidx);
      float4 u1 = *(const float4*)(Af + aidx + 4);
      av[0]=f2s(u0.x); av[1]=f2s(u0.y); av[2]=f2s(u0.z); av[3]=f2s(u0.w);
      av[4]=f2s(u1.x); av[5]=f2s(u1.y); av[6]=f2s(u1.z); av[7]=f2s(u1.w);
    }
    *(short8*)&sm.g.As[ar*40 + akk] = av;
    size_t wi = (size_t)(k0 + wk)*ldw + wcol + wn;
    short wv[8];
    if (f == 0){
      short8 t8 = *(const short8*)((const short*)W + wi);
      #pragma unroll
      for (int j = 0; j < 8; j++) wv[j] = t8[j];
    } else {
      const float* Wf = (const float*)W;
      float4 u0 = *(const float4*)(Wf + wi);
      float4 u1 = *(const float4*)(Wf + wi + 4);
      wv[0]=f2s(u0.x); wv[1]=f2s(u0.y); wv[2]=f2s(u0.z); wv[3]=f2s(u0.w);
      wv[4]=f2s(u1.x); wv[5]=f2s(u1.y); wv[6]=f2s(u1.z); wv[7]=f2s(u1.w);
    }
    #pragma unroll
    for (int j = 0; j < 8; j++){
      int nrow = wn + j;
      int col = (((wk >> 3) ^ ((nrow >> 3) & 3)) << 3) | (wk & 7);
      sm.g.Wt[nrow*40 + col] = wv[j];
    }
    __syncthreads();
    short8 afr = *(const short8*)&sm.g.As[(wave*16 + m)*40 + kq*8];
    #pragma unroll
    for (int t4 = 0; t4 < 4; t4++){
      int nb = t4*16 + m;
      short8 bfr = *(const short8*)&sm.g.Wt[nb*40 + ((kq ^ ((nb >> 3) & 3)) << 3)];
      acc[t4] = __builtin_amdgcn_mfma_f32_16x16x32_bf16(afr, bfr, acc[t4], 0, 0, 0);
    }
    __syncthreads();
  }
  #pragma unroll
  for (int t4 = 0; t4 < 4; t4++){
    int c = ccol0 + t4*16 + m;
    float bv = bias ? ldI(bias, wcol + t4*16 + m, f) : 0.f;
    #pragma unroll
    for (int reg = 0; reg < 4; reg++){
      int r = row0 + wave*16 + kq*4 + reg;
      float v = acc[t4][reg] + bv;
      if (act == 1) v = fmaxf(v, 0.f);
      C[(size_t)r*ldc + c] = f2b(v);
    }
  }
}

// ---------------- dec_nll 64x64 tile via MFMA (bf16 z), accumulates ts/P/Q ----------------
__device__ void dec_tile(const KP& p, SMem& sm, int tid, int t, int u, int f){
  __syncthreads();
  int i0 = (u >> 6)*64, j0 = (u & 63)*64;
  size_t aoff = (size_t)t*N*N;
  #pragma unroll
  for (int i = 0; i < 2; i++){
    int idx = tid + i*256;                 // 512 chunk-slots: r = idx>>3, chunk c = idx&7
    int r = idx >> 3, c = idx & 7;
    int col = ((c ^ ((r >> 3) & 3)) << 3);
    *(short8*)&sm.z.Zi[r*72 + col] = *(const short8*)((const short*)p.zbf + (size_t)(i0+r)*ZD + c*8);
    *(short8*)&sm.z.Zj[r*72 + col] = *(const short8*)((const short*)p.zbf + (size_t)(j0+r)*ZD + c*8);
  }
  __syncthreads();
  int wave = tid >> 6, lane = tid & 63, m = lane & 15, kq = lane >> 4;
  int ra = wave*16 + m, sa = (ra >> 3) & 3;
  short8 a1 = *(const short8*)&sm.z.Zi[ra*72 + ((kq ^ sa) << 3)];
  short8 a2 = *(const short8*)&sm.z.Zi[ra*72 + (((kq+4) ^ sa) << 3)];
  f32x4 acc[4] = {};
  #pragma unroll
  for (int t4 = 0; t4 < 4; t4++){
    int rb = t4*16 + m, sb2 = (rb >> 3) & 3;
    short8 b1 = *(const short8*)&sm.z.Zj[rb*72 + ((kq ^ sb2) << 3)];
    short8 b2 = *(const short8*)&sm.z.Zj[rb*72 + (((kq+4) ^ sb2) << 3)];
    acc[t4] = __builtin_amdgcn_mfma_f32_16x16x32_bf16(a1, b1, acc[t4], 0, 0, 0);
    acc[t4] = __builtin_amdgcn_mfma_f32_16x16x32_bf16(a2, b2, acc[t4], 0, 0, 0);
  }
  float lts = 0.f, lP = 0.f, lQ = 0.f;
  #pragma unroll
  for (int t4 = 0; t4 < 4; t4++){
    #pragma unroll
    for (int reg = 0; reg < 4; reg++){
      int i = i0 + wave*16 + kq*4 + reg;
      int j = j0 + t4*16 + m;
      float av = ldI(p.adj, aoff + (size_t)i*N + j, f);
      float dec = sigm(acc[t4][reg]);
      lts += av;
      lQ += (1.f - av)*log1pf(expf(dec));
      if (av != 0.f) lP += av*log1pf(expf(-dec));
    }
  }
  __syncthreads();
  sm.red[tid] = lts; __syncthreads();
  for (int o = 128; o > 0; o >>= 1){ if (tid < o) sm.red[tid] += sm.red[tid+o]; __syncthreads(); }
  if (tid == 0) atomicAdd(p.scal + 8 + t, sm.red[0]);
  __syncthreads();
  sm.red[tid] = lP; __syncthreads();
  for (int o = 128; o > 0; o >>= 1){ if (tid < o) sm.red[tid] += sm.red[tid+o]; __syncthreads(); }
  if (tid == 0) atomicAdd(p.scal + 12 + t, sm.red[0]);
  __syncthreads();
  sm.red[tid] = lQ; __syncthreads();
  for (int o = 128; o > 0; o >>= 1){ if (tid < o) sm.red[tid] += sm.red[tid+o]; __syncthreads(); }
  if (tid == 0) atomicAdd(p.scal + 16 + t, sm.red[0]);
}

// ---------------- setup kernels ----------------
__global__ __launch_bounds__(256) void setup0_k(KP p){
  int gb = blockIdx.x, tid = threadIdx.x;
  if (gb == 0){ if (tid < 64) p.scal[tid] = 0.f; }
  else if (gb == 1){
    if (tid == 0){
      const unsigned short* u = (const unsigned short*)p.x;
      int big = 0;
      for (int i = 0; i < 256; i++){ int e = (u[i] >> 7) & 0xFF; if (e >= 134) big++; }
      *p.dflag = (big > 16) ? 1 : 0;
    }
  } else {
    p.deg[(gb-2)*256 + tid] = 0;
  }
}

__global__ __launch_bounds__(256) void count_deg_k(KP p){
  int idx = blockIdx.x*256 + threadIdx.x;
  int t = idx >> 16, e = idx & (E-1);
  int dst = p.ei[(size_t)t*2*E + E + e] & (N-1);
  atomicAdd(&p.deg[t*N + dst], 1);
}

// scan+cursor (blocks 0-3) + h0 copy (4-35) + phi_x GEMM (36-1023)
__global__ __launch_bounds__(256) void setup2_k(KP p){
  __shared__ SMem sm;
  int gb = blockIdx.x, tid = threadIdx.x;
  int f = *p.dflag;
  if (gb < 4){
    int t = gb;
    const int* dg = p.deg + t*N;
    int* of = p.offs + t*(N+1);
    int base = tid*16;
    int loc[16]; int s = 0;
    #pragma unroll
    for (int i = 0; i < 16; i++){ loc[i] = s; s += dg[base+i]; }
    sm.sh[tid] = s;
    __syncthreads();
    for (int o = 1; o < 256; o <<= 1){
      int v = (tid >= o) ? sm.sh[tid-o] : 0;
      __syncthreads();
      sm.sh[tid] += v;
      __syncthreads();
    }
    int pre = (tid == 0) ? 0 : sm.sh[tid-1];
    #pragma unroll
    for (int i = 0; i < 16; i++){
      int deg_i = dg[base+i];
      of[base+i] = pre + loc[i];
      p.dinv[t*N + base + i] = rsqrtf(1.f + (float)deg_i);
    }
    if (tid == 255) of[N] = sm.sh[255];
    __syncthreads();
    #pragma unroll
    for (int i = 0; i < 16; i++) p.deg[t*N + base + i] = pre + loc[i];  // cursor
  } else if (gb < 36){
    for (int idx = (gb-4)*256 + tid; idx < N*HD; idx += 32*256){
      float v = ldI(p.h0, idx, f);
      p.h_prev[idx] = v; p.h_bf[idx] = f2b(v);
    }
  } else {
    for (int u = gb - 36; u < 1024; u += 988){
      int colblk = u & 3, rowblk = u >> 2;
      mfma_tile(sm, tid, f, p.x, 1, XD, nullptr, 0, 0, XD, XD,
                p.phi_x_w, HD, colblk*64, p.phi_x_b, 1,
                p.phiXa, HD, rowblk*64, colblk*64);
    }
  }
}

__global__ __launch_bounds__(256) void scatter_k(KP p){
  int idx = blockIdx.x*256 + threadIdx.x;
  int t = idx >> 16, e = idx & (E-1);
  int s = p.ei[(size_t)t*2*E + e] & (N-1);
  int d = p.ei[(size_t)t*2*E + E + e] & (N-1);
  int pos = atomicAdd(&p.deg[t*N + d], 1);
  if (pos >= 0 && pos < E){
    p.srcs[(size_t)t*E + pos] = s;
    p.enorm[(size_t)t*E + pos] = p.dinv[t*N + s] * p.dinv[t*N + d];
  }
}

// ---------------- step kernels ----------------
__global__ __launch_bounds__(256) void g1_k(KP p, int t){   // grid 1024
  __shared__ SMem sm;
  int gb = blockIdx.x, tid = threadIdx.x, f = *p.dflag;
  const bf16* phiX = p.phiXa + (size_t)t*N*HD;
  int colblk = gb & 15, rowblk = gb >> 4;
  int grp = colblk >> 2, c4 = colblk & 3;
  if (grp == 0)
    mfma_tile(sm, tid, f, phiX, 2, HD, p.h_bf, 2, HD, 256, 512,
              p.enc_w, HD, c4*64, nullptr, 0, p.Gs1, 1024, rowblk*64, colblk*64);
  else if (grp == 1)
    mfma_tile(sm, tid, f, p.h_bf, 2, HD, nullptr, 0, 0, 256, 256,
              p.prior_w, HD, c4*64, p.prior_b, 1, p.Gs1, 1024, rowblk*64, colblk*64);
  else if (grp == 2)
    mfma_tile(sm, tid, f, p.h_bf, 2, HD, nullptr, 0, 0, 256, 256,
              p.ghz, HD, c4*64, nullptr, 0, p.Gs1, 1024, rowblk*64, colblk*64);
  else
    mfma_tile(sm, tid, f, p.h_bf, 2, HD, nullptr, 0, 0, 256, 256,
              p.ghr, HD, c4*64, nullptr, 0, p.Gs1, 1024, rowblk*64, colblk*64);
}

__global__ __launch_bounds__(256) void encagg_pms_k(KP p, int t){   // grid 640
  __shared__ SMem sm;
  int gb = blockIdx.x, tid = threadIdx.x, f = *p.dflag;
  const int* offs_t = p.offs + t*(N+1);
  const int* srcs_t = p.srcs + (size_t)t*E;
  const float* en_t = p.enorm + (size_t)t*E;
  const float* dv_t = p.dinv + t*N;
  if (gb < 512){
    int g8 = tid >> 5, l = tid & 31;
    int n = gb*8 + g8, c = l*8;
    int e0 = offs_t[n], e1 = offs_t[n+1];
    float d2 = dv_t[n]*dv_t[n];
    float acc[8], v[8];
    ld8b(p.Gs1 + (size_t)n*1024 + c, v);
    #pragma unroll
    for (int j = 0; j < 8; j++) acc[j] = d2 * v[j];
    for (int e = e0; e < e1; e++){
      int s = srcs_t[e] & (N-1);
      float nm = en_t[e];
      ld8b(p.Gs1 + (size_t)s*1024 + c, v);
      #pragma unroll
      for (int j = 0; j < 8; j++) acc[j] += nm * v[j];
    }
    #pragma unroll
    for (int j = 0; j < 8; j++) acc[j] = fmaxf(acc[j] + ldI(p.enc_b, c + j, f), 0.f);
    uint4 o; o.x = pack2(acc[0],acc[1]); o.y = pack2(acc[2],acc[3]);
    o.z = pack2(acc[4],acc[5]); o.w = pack2(acc[6],acc[7]);
    *(uint4*)(p.Tb1 + (size_t)n*HD + c) = o;
  } else {
    int u = gb - 512;
    int colblk = u & 1, rowblk = u >> 1;
    mfma_tile(sm, tid, f, p.Gs1 + 256, 2, 1024, nullptr, 0, 0, 256, 256,
              colblk ? p.prior_std_w : p.prior_mean_w, ZD, 0,
              colblk ? p.prior_std_b : p.prior_mean_b, 0,
              p.Gms, 256, rowblk*64, 128 + colblk*64);
  }
}

__global__ __launch_bounds__(256) void encms_k(KP p, int t){   // grid 128
  __shared__ SMem sm;
  int gb = blockIdx.x, tid = threadIdx.x, f = *p.dflag;
  int colblk = gb & 1, rowblk = gb >> 1;
  mfma_tile(sm, tid, f, p.Tb1, 2, HD, nullptr, 0, 0, 256, 256,
            colblk ? p.enc_std_w : p.enc_mean_w, ZD, 0, nullptr, 0,
            p.Gms, 256, rowblk*64, colblk*64);
}

// fused: enc mean/std aggregation + reparam + outputs + kld (grid 256)
__global__ __launch_bounds__(256) void msaggpost_k(KP p, int t){
  __shared__ SMem sm;
  int gb = blockIdx.x, tid = threadIdx.x, f = *p.dflag;
  const int* offs_t = p.offs + t*(N+1);
  const int* srcs_t = p.srcs + (size_t)t*E;
  const float* en_t = p.enorm + (size_t)t*E;
  const float* dv_t = p.dinv + t*N;
  int g16 = tid >> 4, l = tid & 15;
  int n = gb*16 + g16, c = l*8;
  {
    int e0 = offs_t[n], e1 = offs_t[n+1];
    float d2 = dv_t[n]*dv_t[n];
    float acc[8], v[8];
    ld8b(p.Gms + (size_t)n*256 + c, v);
    #pragma unroll
    for (int j = 0; j < 8; j++) acc[j] = d2 * v[j];
    for (int e = e0; e < e1; e++){
      int s = srcs_t[e] & (N-1);
      float nm = en_t[e];
      ld8b(p.Gms + (size_t)s*256 + c, v);
      #pragma unroll
      for (int j = 0; j < 8; j++) acc[j] += nm * v[j];
    }
    #pragma unroll
    for (int j = 0; j < 8; j++) sm.m.msh[g16*128 + c + j] = acc[j];
  }
  __syncthreads();
  float el = 0.f;
  {
    int d0 = l*4;
    #pragma unroll
    for (int q = 0; q < 4; q++){
      int d = d0 + q;
      size_t idx = (size_t)n*ZD + d;
      float mean = sm.m.msh[g16*128 + d] + ldI(p.enc_mean_b, d, f);
      float sd = splus(sm.m.msh[g16*128 + 64 + d] + ldI(p.enc_std_b, d, f));
      float zv = ldI(p.eps, (size_t)t*N*ZD + idx, f) * sd + mean;
      p.zbf[idx] = f2b(zv);
      stO(p.out, OUT_EM + (size_t)t*N*ZD + idx, mean, f);
      float pm = b2f(p.Gms[(size_t)n*256 + 128 + d]);
      float ps = splus(b2f(p.Gms[(size_t)n*256 + 192 + d]));
      stO(p.out, OUT_PM + (size_t)t*N*ZD + idx, pm, f);
      float s1 = sd + 1e-10f, s2 = ps + 1e-10f;
      float dm = mean - pm;
      el += 2.f*(logf(s2) - logf(s1)) - (s1*s1 + dm*dm)/(s2*s2) + 1.f;
    }
  }
  __syncthreads();
  sm.red[tid] = el; __syncthreads();
  for (int o = 128; o > 0; o >>= 1){ if (tid < o) sm.red[tid] += sm.red[tid+o]; __syncthreads(); }
  if (tid == 0) atomicAdd(p.scal + 4, sm.red[0] * (0.5f/((float)N*(float)ZD)));
}

__global__ __launch_bounds__(256) void phiz_dec_k(KP p, int t){   // grid 1024
  __shared__ SMem sm;
  int gb = blockIdx.x, tid = threadIdx.x, f = *p.dflag;
  if (gb < 256){
    int colblk = gb & 3, rowblk = gb >> 2;
    mfma_tile(sm, tid, f, p.zbf, 2, ZD, nullptr, 0, 0, ZD, ZD,
              p.phi_z_w, HD, colblk*64, p.phi_z_b, 1, p.Tb2, HD, rowblk*64, colblk*64);
  } else {
    int base = (gb - 256)*4;
    for (int i = 0; i < 4; i++) dec_tile(p, sm, tid, t, base + i, f);
  }
}

__global__ __launch_bounds__(256) void grux_dec_k(KP p, int t){   // grid 1024
  __shared__ SMem sm;
  int gb = blockIdx.x, tid = threadIdx.x, f = *p.dflag;
  const bf16* phiX = p.phiXa + (size_t)t*N*HD;
  if (gb < 768){
    int colblk = gb % 12, rowblk = gb / 12;
    int grp = colblk >> 2, c4 = colblk & 3;
    const void* W = (grp == 0) ? p.gxz : ((grp == 1) ? p.gxr : p.gxh);
    mfma_tile(sm, tid, f, phiX, 2, HD, p.Tb2, 2, HD, 256, 512,
              W, HD, c4*64, nullptr, 0, p.Gsx, 768, rowblk*64, colblk*64);
  } else {
    int base = 3072 + (gb - 768)*4;
    for (int i = 0; i < 4; i++) dec_tile(p, sm, tid, t, base + i, f);
  }
}

__global__ __launch_bounds__(256) void zr_k(KP p, int t){   // grid 1024
  int gb = blockIdx.x, tid = threadIdx.x;
  const int* offs_t = p.offs + t*(N+1);
  const int* srcs_t = p.srcs + (size_t)t*E;
  const float* en_t = p.enorm + (size_t)t*E;
  const float* dv_t = p.dinv + t*N;
  int g4 = tid >> 6, lane = tid & 63;
  int n = gb*4 + g4, c = lane*8;
  int e0 = offs_t[n], e1 = offs_t[n+1];
  float d2 = dv_t[n]*dv_t[n];
  float acc[8], v1[8], v2[8];
  ld8b(p.Gsx + (size_t)n*768 + c, v1);
  ld8b(p.Gs1 + 512 + (size_t)n*1024 + c, v2);
  #pragma unroll
  for (int j = 0; j < 8; j++) acc[j] = d2 * (v1[j] + v2[j]);
  for (int e = e0; e < e1; e++){
    int s = srcs_t[e] & (N-1);
    float nm = en_t[e];
    ld8b(p.Gsx + (size_t)s*768 + c, v1);
    ld8b(p.Gs1 + 512 + (size_t)s*1024 + c, v2);
    #pragma unroll
    for (int j = 0; j < 8; j++) acc[j] += nm * (v1[j] + v2[j]);
  }
  if (c < 256){
    size_t base = (size_t)n*HD + c;
    float4 o0, o1;
    o0.x = sigm(acc[0]); o0.y = sigm(acc[1]); o0.z = sigm(acc[2]); o0.w = sigm(acc[3]);
    o1.x = sigm(acc[4]); o1.y = sigm(acc[5]); o1.z = sigm(acc[6]); o1.w = sigm(acc[7]);
    *(float4*)(p.z_g + base) = o0;
    *(float4*)(p.z_g + base + 4) = o1;
  } else {
    size_t base = (size_t)n*HD + (c - 256);
    float r[8];
    #pragma unroll
    for (int j = 0; j < 8; j++) r[j] = sigm(acc[j]) * p.h_prev[base+j];
    uint4 o; o.x = pack2(r[0],r[1]); o.y = pack2(r[2],r[3]);
    o.z = pack2(r[4],r[5]); o.w = pack2(r[6],r[7]);
    *(uint4*)(p.Tb1 + base) = o;
  }
}

__global__ __launch_bounds__(256) void hh_k(KP p, int t){   // grid 256
  __shared__ SMem sm;
  int gb = blockIdx.x, tid = threadIdx.x, f = *p.dflag;
  int colblk = gb & 3, rowblk = gb >> 2;
  mfma_tile(sm, tid, f, p.Tb1, 2, HD, nullptr, 0, 0, 256, 256,
            p.ghh, HD, colblk*64, nullptr, 0, p.Gh2, 256, rowblk*64, colblk*64);
}

__global__ __launch_bounds__(256) void hagg_k(KP p, int t){   // grid 512
  int gb = blockIdx.x, tid = threadIdx.x, f = *p.dflag;
  const int* offs_t = p.offs + t*(N+1);
  const int* srcs_t = p.srcs + (size_t)t*E;
  const float* en_t = p.enorm + (size_t)t*E;
  const float* dv_t = p.dinv + t*N;
  int g8 = tid >> 5, l = tid & 31;
  int n = gb*8 + g8, c = l*8;
  int e0 = offs_t[n], e1 = offs_t[n+1];
  float d2 = dv_t[n]*dv_t[n];
  float acc[8], v1[8], v2[8];
  ld8b(p.Gsx + 512 + (size_t)n*768 + c, v1);
  ld8b(p.Gh2 + (size_t)n*256 + c, v2);
  #pragma unroll
  for (int j = 0; j < 8; j++) acc[j] = d2 * (v1[j] + v2[j]);
  for (int e = e0; e < e1; e++){
    int s = srcs_t[e] & (N-1);
    float nm = en_t[e];
    ld8b(p.Gsx + 512 + (size_t)s*768 + c, v1);
    ld8b(p.Gh2 + (size_t)s*256 + c, v2);
    #pragma unroll
    for (int j = 0; j < 8; j++) acc[j] += nm * (v1[j] + v2[j]);
  }
  size_t base = (size_t)n*HD + c;
  #pragma unroll
  for (int j = 0; j < 8; j++){
    float z = p.z_g[base+j];
    float hv = p.h_prev[base+j];
    float nv = z*hv + (1.f - z)*tanhf(acc[j]);
    p.h_prev[base+j] = nv;
    p.h_bf[base+j] = f2b(nv);
    if (t == T_STEPS-1) stO(p.out, OUT_H + base + j, nv, f);
  }
}

__global__ void fin_k(KP p){
  if (threadIdx.x == 0){
    int f = *p.dflag;
    const float NNf = 16777216.f;
    float nll = 0.f;
    for (int t = 0; t < T_STEPS; t++){
      float ts = p.scal[8+t], P = p.scal[12+t], Q = p.scal[16+t];
      float posw = (NNf - ts)/ts;
      nll += (posw*P + Q) * 0.5f/(NNf - ts);
    }
    stO(p.out, 0, p.scal[4], f);
    stO(p.out, 1, nll, f);
  }
}

// ---------------- host ----------------
extern "C" void kernel_launch(void* const* d_in, const int* in_sizes, int n_in,
                              void* d_out, int out_size, void* d_ws, size_t ws_size,
                              hipStream_t stream){
  KP P;
  P.x = d_in[0];  P.ei = (const int*)d_in[1];  P.adj = d_in[2];  P.eps = d_in[3];  P.h0 = d_in[4];
  P.phi_x_w = d_in[5];  P.phi_x_b = d_in[6];  P.phi_z_w = d_in[7];  P.phi_z_b = d_in[8];
  P.enc_w = d_in[9];  P.enc_b = d_in[10];
  P.enc_mean_w = d_in[11];  P.enc_mean_b = d_in[12];
  P.enc_std_w = d_in[13];   P.enc_std_b = d_in[14];
  P.prior_w = d_in[15];  P.prior_b = d_in[16];
  P.prior_mean_w = d_in[17];  P.prior_mean_b = d_in[18];
  P.prior_std_w = d_in[19];   P.prior_std_b = d_in[20];
  P.gxz = d_in[21];  P.ghz = d_in[22];  P.gxr = d_in[23];
  P.ghr = d_in[24];  P.gxh = d_in[25];  P.ghh = d_in[26];
  P.out = d_out;

  char* wp = (char*)d_ws;
  auto alloc = [&](size_t bytes){ void* q = (void*)wp; wp += (bytes + 255) & ~(size_t)255; return q; };
  P.scal  = (float*)alloc(64*sizeof(float));
  P.dflag = (int*)  alloc(256);
  P.dinv  = (float*)alloc((size_t)T_STEPS*N*4);
  P.offs  = (int*)  alloc((size_t)T_STEPS*(N+1)*4);
  P.srcs  = (int*)  alloc((size_t)T_STEPS*E*4);
  P.enorm = (float*)alloc((size_t)T_STEPS*E*4);
  P.deg   = (int*)  alloc((size_t)T_STEPS*N*4);
  P.h_prev= (float*)alloc((size_t)N*HD*4);
  P.h_bf  = (bf16*) alloc((size_t)N*HD*2);
  P.phiXa = (bf16*) alloc((size_t)T_STEPS*N*HD*2);
  P.Tb1   = (bf16*) alloc((size_t)N*HD*2);
  P.Tb2   = (bf16*) alloc((size_t)N*HD*2);
  P.zbf   = (bf16*) alloc((size_t)N*ZD*2);
  P.z_g   = (float*)alloc((size_t)N*HD*4);
  P.Gs1   = (bf16*) alloc((size_t)N*1024*2);
  P.Gsx   = (bf16*) alloc((size_t)N*768*2);
  P.Gms   = (bf16*) alloc((size_t)N*256*2);
  P.Gh2   = (bf16*) alloc((size_t)N*256*2);

  setup0_k<<<66,256,0,stream>>>(P);
  count_deg_k<<<1024,256,0,stream>>>(P);
  setup2_k<<<1024,256,0,stream>>>(P);
  scatter_k<<<1024,256,0,stream>>>(P);
  for (int t = 0; t < T_STEPS; t++){
    g1_k<<<1024,256,0,stream>>>(P, t);
    encagg_pms_k<<<640,256,0,stream>>>(P, t);
    encms_k<<<128,256,0,stream>>>(P, t);
    msaggpost_k<<<256,256,0,stream>>>(P, t);
    phiz_dec_k<<<1024,256,0,stream>>>(P, t);
    grux_dec_k<<<1024,256,0,stream>>>(P, t);
    zr_k<<<1024,256,0,stream>>>(P, t);
    hh_k<<<256,256,0,stream>>>(P, t);
    hagg_k<<<512,256,0,stream>>>(P, t);
  }
  fin_k<<<1,64,0,stream>>>(P);
}

// Round 9
// 1545.637 us; speedup vs baseline: 4.8542x; 1.2088x over previous
//
#include <hip/hip_runtime.h>
#include <hip/hip_bf16.h>

#define T_STEPS 4
#define N 4096
#define E 65536
#define XD 256
#define HD 256
#define ZD 64

typedef __hip_bfloat16 bf16;
typedef __attribute__((ext_vector_type(8))) short short8;
typedef __attribute__((ext_vector_type(4))) float f32x4;

__device__ __forceinline__ float b2f(bf16 v){ return __bfloat162float(v); }
__device__ __forceinline__ bf16 f2b(float v){ return __float2bfloat16(v); }
__device__ __forceinline__ short f2s(float v){ return __builtin_bit_cast(short, f2b(v)); }
__device__ __forceinline__ float bits2f(unsigned int s){ return __builtin_bit_cast(float, s << 16); }
__device__ __forceinline__ float s2f(short s){ return bits2f((unsigned int)(unsigned short)s); }
__device__ __forceinline__ float splus(float x){ return (x > 20.f) ? x : log1pf(expf(x)); }
__device__ __forceinline__ float sigm(float x){ return 1.f/(1.f + expf(-x)); }

__device__ __forceinline__ float ldI(const void* p, size_t i, int f){
  return f ? ((const float*)p)[i] : b2f(((const bf16*)p)[i]);
}
__device__ __forceinline__ void stO(void* p, size_t i, float v, int f){
  if (f) ((float*)p)[i] = v; else ((bf16*)p)[i] = f2b(v);
}
__device__ __forceinline__ void ld8b(const bf16* p, float v[8]){
  uint4 u = *(const uint4*)p;
  v[0]=bits2f(u.x & 0xffffu); v[1]=bits2f(u.x >> 16);
  v[2]=bits2f(u.y & 0xffffu); v[3]=bits2f(u.y >> 16);
  v[4]=bits2f(u.z & 0xffffu); v[5]=bits2f(u.z >> 16);
  v[6]=bits2f(u.w & 0xffffu); v[7]=bits2f(u.w >> 16);
}
__device__ __forceinline__ unsigned int pack2(float a, float b){
  return (unsigned int)(unsigned short)__builtin_bit_cast(unsigned short, f2b(a))
       | ((unsigned int)(unsigned short)__builtin_bit_cast(unsigned short, f2b(b)) << 16);
}

union SMem {
  struct { short As[64*40]; short Wt[64*40]; } g;                        // 10.2 KB (GEMM)
  struct { short Zi[64*72]; short Zj[64*72]; short Adj[64*72]; float red[256]; } z; // 28.7 KB
  struct { float msh[16*128]; } m;                                       // 8 KB
  int sh[256];
  float red[256];
};

struct KP {
  const void *x, *adj, *eps, *h0;
  const int* ei;
  const void *phi_x_w, *phi_x_b, *phi_z_w, *phi_z_b;
  const void *enc_w, *enc_b, *enc_mean_w, *enc_mean_b, *enc_std_w, *enc_std_b;
  const void *prior_w, *prior_b, *prior_mean_w, *prior_mean_b, *prior_std_w, *prior_std_b;
  const void *gxz, *ghz, *gxr, *ghr, *gxh, *ghh;
  void* out;
  float* scal; int* dflag; float* dinv; int* offs; int* srcs; float* enorm; int* deg;
  float* h_prev; bf16* h_bf; bf16* phiXa; bf16* Tb1; bf16* Tb2;
  bf16* zbf; float* z_g; bf16* Gs1; bf16* Gsx; bf16* Gms; bf16* Gh2;
};

#define OUT_EM ((size_t)2)
#define OUT_PM ((size_t)(2 + (size_t)T_STEPS*N*ZD))
#define OUT_H  ((size_t)(2 + (size_t)2*T_STEPS*N*ZD))

// ---------------- MFMA 64x64 tile: C = [A1|A2] @ W(+bias)(+relu), bf16 out ----------------
// Wt LDS layout XOR-chunk-swizzled (2-way max on writes).
__device__ void mfma_tile(SMem& sm, int tid, int f,
    const void* A1, int am1, int lda1, const void* A2, int am2, int lda2,
    int K1, int K, const void* W, int ldw, int wcol,
    const void* bias, int act, bf16* C, int ldc, int row0, int ccol0){
  int ar = tid >> 2, akk = (tid & 3)*8;
  int wk = tid >> 3, wn = (tid & 7)*8;
  int wave = tid >> 6, lane = tid & 63, m = lane & 15, kq = lane >> 4;
  f32x4 acc[4] = {};
  for (int k0 = 0; k0 < K; k0 += 32){
    const void* A; int am, lda, kb;
    if (k0 < K1){ A = A1; am = am1; lda = lda1; kb = k0; }
    else        { A = A2; am = am2; lda = lda2; kb = k0 - K1; }
    size_t aidx = (size_t)(row0 + ar)*lda + kb + akk;
    short8 av;
    if (am == 2 || (am == 1 && f == 0)){
      av = *(const short8*)((const short*)A + aidx);
    } else {
      const float* Af = (const float*)A;
      float4 u0 = *(const float4*)(Af + aidx);
      float4 u1 = *(const float4*)(Af + aidx + 4);
      av[0]=f2s(u0.x); av[1]=f2s(u0.y); av[2]=f2s(u0.z); av[3]=f2s(u0.w);
      av[4]=f2s(u1.x); av[5]=f2s(u1.y); av[6]=f2s(u1.z); av[7]=f2s(u1.w);
    }
    *(short8*)&sm.g.As[ar*40 + akk] = av;
    size_t wi = (size_t)(k0 + wk)*ldw + wcol + wn;
    short wv[8];
    if (f == 0){
      short8 t8 = *(const short8*)((const short*)W + wi);
      #pragma unroll
      for (int j = 0; j < 8; j++) wv[j] = t8[j];
    } else {
      const float* Wf = (const float*)W;
      float4 u0 = *(const float4*)(Wf + wi);
      float4 u1 = *(const float4*)(Wf + wi + 4);
      wv[0]=f2s(u0.x); wv[1]=f2s(u0.y); wv[2]=f2s(u0.z); wv[3]=f2s(u0.w);
      wv[4]=f2s(u1.x); wv[5]=f2s(u1.y); wv[6]=f2s(u1.z); wv[7]=f2s(u1.w);
    }
    #pragma unroll
    for (int j = 0; j < 8; j++){
      int nrow = wn + j;
      int col = (((wk >> 3) ^ ((nrow >> 3) & 3)) << 3) | (wk & 7);
      sm.g.Wt[nrow*40 + col] = wv[j];
    }
    __syncthreads();
    short8 afr = *(const short8*)&sm.g.As[(wave*16 + m)*40 + kq*8];
    #pragma unroll
    for (int t4 = 0; t4 < 4; t4++){
      int nb = t4*16 + m;
      short8 bfr = *(const short8*)&sm.g.Wt[nb*40 + ((kq ^ ((nb >> 3) & 3)) << 3)];
      acc[t4] = __builtin_amdgcn_mfma_f32_16x16x32_bf16(afr, bfr, acc[t4], 0, 0, 0);
    }
    __syncthreads();
  }
  #pragma unroll
  for (int t4 = 0; t4 < 4; t4++){
    int c = ccol0 + t4*16 + m;
    float bv = bias ? ldI(bias, wcol + t4*16 + m, f) : 0.f;
    #pragma unroll
    for (int reg = 0; reg < 4; reg++){
      int r = row0 + wave*16 + kq*4 + reg;
      float v = acc[t4][reg] + bv;
      if (act == 1) v = fmaxf(v, 0.f);
      C[(size_t)r*ldc + c] = f2b(v);
    }
  }
}

// ---------------- dec 64x64 tile via MFMA, one tile per block, adj through LDS ------------
__device__ void dec_tile1(const KP& p, SMem& sm, int tid, int t, int u, int f){
  int i0 = (u >> 6)*64, j0 = (u & 63)*64;
  size_t aoff = (size_t)t*N*N;
  #pragma unroll
  for (int i = 0; i < 2; i++){
    int idx = tid + i*256;                 // r = idx>>3, chunk c = idx&7 (swizzled col)
    int r = idx >> 3, c = idx & 7;
    int col = ((c ^ ((r >> 3) & 3)) << 3);
    *(short8*)&sm.z.Zi[r*72 + col] = *(const short8*)((const short*)p.zbf + (size_t)(i0+r)*ZD + c*8);
    *(short8*)&sm.z.Zj[r*72 + col] = *(const short8*)((const short*)p.zbf + (size_t)(j0+r)*ZD + c*8);
  }
  { // adj tile: 4 threads/row, 16 cols each — 128B contiguous per row, coalesced
    int row = tid >> 2, c0 = (tid & 3)*16;
    if (f){
      const float* ap = (const float*)p.adj + aoff + (size_t)(i0+row)*N + j0 + c0;
      short tmp[16];
      #pragma unroll
      for (int q = 0; q < 16; q += 4){
        float4 v = *(const float4*)(ap + q);
        tmp[q]=f2s(v.x); tmp[q+1]=f2s(v.y); tmp[q+2]=f2s(v.z); tmp[q+3]=f2s(v.w);
      }
      *(short8*)&sm.z.Adj[row*72 + c0]     = *(short8*)&tmp[0];
      *(short8*)&sm.z.Adj[row*72 + c0 + 8] = *(short8*)&tmp[8];
    } else {
      const short* ap = (const short*)p.adj + aoff + (size_t)(i0+row)*N + j0 + c0;
      *(short8*)&sm.z.Adj[row*72 + c0]     = *(const short8*)ap;
      *(short8*)&sm.z.Adj[row*72 + c0 + 8] = *(const short8*)(ap + 8);
    }
  }
  __syncthreads();
  int wave = tid >> 6, lane = tid & 63, m = lane & 15, kq = lane >> 4;
  int ra = wave*16 + m, sa = (ra >> 3) & 3;
  short8 a1 = *(const short8*)&sm.z.Zi[ra*72 + ((kq ^ sa) << 3)];
  short8 a2 = *(const short8*)&sm.z.Zi[ra*72 + (((kq+4) ^ sa) << 3)];
  f32x4 acc[4] = {};
  #pragma unroll
  for (int t4 = 0; t4 < 4; t4++){
    int rb = t4*16 + m, sb2 = (rb >> 3) & 3;
    short8 b1 = *(const short8*)&sm.z.Zj[rb*72 + ((kq ^ sb2) << 3)];
    short8 b2 = *(const short8*)&sm.z.Zj[rb*72 + (((kq+4) ^ sb2) << 3)];
    acc[t4] = __builtin_amdgcn_mfma_f32_16x16x32_bf16(a1, b1, acc[t4], 0, 0, 0);
    acc[t4] = __builtin_amdgcn_mfma_f32_16x16x32_bf16(a2, b2, acc[t4], 0, 0, 0);
  }
  float lts = 0.f, lP = 0.f, lQ = 0.f;
  #pragma unroll
  for (int t4 = 0; t4 < 4; t4++){
    int lj = t4*16 + m;
    #pragma unroll
    for (int reg = 0; reg < 4; reg++){
      int li = wave*16 + kq*4 + reg;
      float av = s2f(sm.z.Adj[li*72 + lj]);   // 2 lanes/bank -> free
      float dec = sigm(acc[t4][reg]);
      lts += av;
      lQ += (1.f - av)*log1pf(expf(dec));
      if (av != 0.f) lP += av*log1pf(expf(-dec));
    }
  }
  __syncthreads();
  sm.z.red[tid] = lts; __syncthreads();
  for (int o = 128; o > 0; o >>= 1){ if (tid < o) sm.z.red[tid] += sm.z.red[tid+o]; __syncthreads(); }
  if (tid == 0) atomicAdd(p.scal + 8 + t, sm.z.red[0]);
  __syncthreads();
  sm.z.red[tid] = lP; __syncthreads();
  for (int o = 128; o > 0; o >>= 1){ if (tid < o) sm.z.red[tid] += sm.z.red[tid+o]; __syncthreads(); }
  if (tid == 0) atomicAdd(p.scal + 12 + t, sm.z.red[0]);
  __syncthreads();
  sm.z.red[tid] = lQ; __syncthreads();
  for (int o = 128; o > 0; o >>= 1){ if (tid < o) sm.z.red[tid] += sm.z.red[tid+o]; __syncthreads(); }
  if (tid == 0) atomicAdd(p.scal + 16 + t, sm.z.red[0]);
}

// ---------------- setup kernels ----------------
__global__ __launch_bounds__(256) void setup0_k(KP p){
  int gb = blockIdx.x, tid = threadIdx.x;
  if (gb == 0){ if (tid < 64) p.scal[tid] = 0.f; }
  else if (gb == 1){
    if (tid == 0){
      const unsigned short* u = (const unsigned short*)p.x;
      int big = 0;
      for (int i = 0; i < 256; i++){ int e = (u[i] >> 7) & 0xFF; if (e >= 134) big++; }
      *p.dflag = (big > 16) ? 1 : 0;
    }
  } else {
    p.deg[(gb-2)*256 + tid] = 0;
  }
}

__global__ __launch_bounds__(256) void count_deg_k(KP p){
  int idx = blockIdx.x*256 + threadIdx.x;
  int t = idx >> 16, e = idx & (E-1);
  int dst = p.ei[(size_t)t*2*E + E + e] & (N-1);
  atomicAdd(&p.deg[t*N + dst], 1);
}

// scan+cursor (0-3) + h0 copy (4-35) + phi_x GEMM (36-1023)
__global__ __launch_bounds__(256) void setup2_k(KP p){
  __shared__ SMem sm;
  int gb = blockIdx.x, tid = threadIdx.x;
  int f = *p.dflag;
  if (gb < 4){
    int t = gb;
    const int* dg = p.deg + t*N;
    int* of = p.offs + t*(N+1);
    int base = tid*16;
    int loc[16]; int s = 0;
    #pragma unroll
    for (int i = 0; i < 16; i++){ loc[i] = s; s += dg[base+i]; }
    sm.sh[tid] = s;
    __syncthreads();
    for (int o = 1; o < 256; o <<= 1){
      int v = (tid >= o) ? sm.sh[tid-o] : 0;
      __syncthreads();
      sm.sh[tid] += v;
      __syncthreads();
    }
    int pre = (tid == 0) ? 0 : sm.sh[tid-1];
    #pragma unroll
    for (int i = 0; i < 16; i++){
      int deg_i = dg[base+i];
      of[base+i] = pre + loc[i];
      p.dinv[t*N + base + i] = rsqrtf(1.f + (float)deg_i);
    }
    if (tid == 255) of[N] = sm.sh[255];
    __syncthreads();
    #pragma unroll
    for (int i = 0; i < 16; i++) p.deg[t*N + base + i] = pre + loc[i];  // cursor
  } else if (gb < 36){
    for (int idx = (gb-4)*256 + tid; idx < N*HD; idx += 32*256){
      float v = ldI(p.h0, idx, f);
      p.h_prev[idx] = v; p.h_bf[idx] = f2b(v);
    }
  } else {
    for (int u = gb - 36; u < 1024; u += 988){
      int colblk = u & 3, rowblk = u >> 2;
      mfma_tile(sm, tid, f, p.x, 1, XD, nullptr, 0, 0, XD, XD,
                p.phi_x_w, HD, colblk*64, p.phi_x_b, 1,
                p.phiXa, HD, rowblk*64, colblk*64);
    }
  }
}

__global__ __launch_bounds__(256) void scatter_k(KP p){
  int idx = blockIdx.x*256 + threadIdx.x;
  int t = idx >> 16, e = idx & (E-1);
  int s = p.ei[(size_t)t*2*E + e] & (N-1);
  int d = p.ei[(size_t)t*2*E + E + e] & (N-1);
  int pos = atomicAdd(&p.deg[t*N + d], 1);
  if (pos >= 0 && pos < E){
    p.srcs[(size_t)t*E + pos] = s;
    p.enorm[(size_t)t*E + pos] = p.dinv[t*N + s] * p.dinv[t*N + d];
  }
}

// ---------------- step kernels ----------------
__global__ __launch_bounds__(256) void g1_k(KP p, int t){   // grid 1024
  __shared__ SMem sm;
  int gb = blockIdx.x, tid = threadIdx.x, f = *p.dflag;
  const bf16* phiX = p.phiXa + (size_t)t*N*HD;
  int colblk = gb & 15, rowblk = gb >> 4;
  int grp = colblk >> 2, c4 = colblk & 3;
  if (grp == 0)
    mfma_tile(sm, tid, f, phiX, 2, HD, p.h_bf, 2, HD, 256, 512,
              p.enc_w, HD, c4*64, nullptr, 0, p.Gs1, 1024, rowblk*64, colblk*64);
  else if (grp == 1)
    mfma_tile(sm, tid, f, p.h_bf, 2, HD, nullptr, 0, 0, 256, 256,
              p.prior_w, HD, c4*64, p.prior_b, 1, p.Gs1, 1024, rowblk*64, colblk*64);
  else if (grp == 2)
    mfma_tile(sm, tid, f, p.h_bf, 2, HD, nullptr, 0, 0, 256, 256,
              p.ghz, HD, c4*64, nullptr, 0, p.Gs1, 1024, rowblk*64, colblk*64);
  else
    mfma_tile(sm, tid, f, p.h_bf, 2, HD, nullptr, 0, 0, 256, 256,
              p.ghr, HD, c4*64, nullptr, 0, p.Gs1, 1024, rowblk*64, colblk*64);
}

__global__ __launch_bounds__(256) void encagg_pms_k(KP p, int t){   // grid 640
  __shared__ SMem sm;
  int gb = blockIdx.x, tid = threadIdx.x, f = *p.dflag;
  const int* offs_t = p.offs + t*(N+1);
  const int* srcs_t = p.srcs + (size_t)t*E;
  const float* en_t = p.enorm + (size_t)t*E;
  const float* dv_t = p.dinv + t*N;
  if (gb < 512){
    int g8 = tid >> 5, l = tid & 31;
    int n = gb*8 + g8, c = l*8;
    int e0 = offs_t[n], e1 = offs_t[n+1];
    float d2 = dv_t[n]*dv_t[n];
    float acc[8], v[8];
    ld8b(p.Gs1 + (size_t)n*1024 + c, v);
    #pragma unroll
    for (int j = 0; j < 8; j++) acc[j] = d2 * v[j];
    for (int e = e0; e < e1; e++){
      int s = srcs_t[e] & (N-1);
      float nm = en_t[e];
      ld8b(p.Gs1 + (size_t)s*1024 + c, v);
      #pragma unroll
      for (int j = 0; j < 8; j++) acc[j] += nm * v[j];
    }
    #pragma unroll
    for (int j = 0; j < 8; j++) acc[j] = fmaxf(acc[j] + ldI(p.enc_b, c + j, f), 0.f);
    uint4 o; o.x = pack2(acc[0],acc[1]); o.y = pack2(acc[2],acc[3]);
    o.z = pack2(acc[4],acc[5]); o.w = pack2(acc[6],acc[7]);
    *(uint4*)(p.Tb1 + (size_t)n*HD + c) = o;
  } else {
    int u = gb - 512;
    int colblk = u & 1, rowblk = u >> 1;
    mfma_tile(sm, tid, f, p.Gs1 + 256, 2, 1024, nullptr, 0, 0, 256, 256,
              colblk ? p.prior_std_w : p.prior_mean_w, ZD, 0,
              colblk ? p.prior_std_b : p.prior_mean_b, 0,
              p.Gms, 256, rowblk*64, 128 + colblk*64);
  }
}

__global__ __launch_bounds__(256) void encms_k(KP p, int t){   // grid 128
  __shared__ SMem sm;
  int gb = blockIdx.x, tid = threadIdx.x, f = *p.dflag;
  int colblk = gb & 1, rowblk = gb >> 1;
  mfma_tile(sm, tid, f, p.Tb1, 2, HD, nullptr, 0, 0, 256, 256,
            colblk ? p.enc_std_w : p.enc_mean_w, ZD, 0, nullptr, 0,
            p.Gms, 256, rowblk*64, colblk*64);
}

// fused: enc mean/std aggregation + reparam + outputs + kld (grid 256)
__global__ __launch_bounds__(256) void msaggpost_k(KP p, int t){
  __shared__ SMem sm;
  int gb = blockIdx.x, tid = threadIdx.x, f = *p.dflag;
  const int* offs_t = p.offs + t*(N+1);
  const int* srcs_t = p.srcs + (size_t)t*E;
  const float* en_t = p.enorm + (size_t)t*E;
  const float* dv_t = p.dinv + t*N;
  int g16 = tid >> 4, l = tid & 15;
  int n = gb*16 + g16, c = l*8;
  {
    int e0 = offs_t[n], e1 = offs_t[n+1];
    float d2 = dv_t[n]*dv_t[n];
    float acc[8], v[8];
    ld8b(p.Gms + (size_t)n*256 + c, v);
    #pragma unroll
    for (int j = 0; j < 8; j++) acc[j] = d2 * v[j];
    for (int e = e0; e < e1; e++){
      int s = srcs_t[e] & (N-1);
      float nm = en_t[e];
      ld8b(p.Gms + (size_t)s*256 + c, v);
      #pragma unroll
      for (int j = 0; j < 8; j++) acc[j] += nm * v[j];
    }
    #pragma unroll
    for (int j = 0; j < 8; j++) sm.m.msh[g16*128 + c + j] = acc[j];
  }
  __syncthreads();
  float el = 0.f;
  {
    int d0 = l*4;
    #pragma unroll
    for (int q = 0; q < 4; q++){
      int d = d0 + q;
      size_t idx = (size_t)n*ZD + d;
      float mean = sm.m.msh[g16*128 + d] + ldI(p.enc_mean_b, d, f);
      float sd = splus(sm.m.msh[g16*128 + 64 + d] + ldI(p.enc_std_b, d, f));
      float zv = ldI(p.eps, (size_t)t*N*ZD + idx, f) * sd + mean;
      p.zbf[idx] = f2b(zv);
      stO(p.out, OUT_EM + (size_t)t*N*ZD + idx, mean, f);
      float pm = b2f(p.Gms[(size_t)n*256 + 128 + d]);
      float ps = splus(b2f(p.Gms[(size_t)n*256 + 192 + d]));
      stO(p.out, OUT_PM + (size_t)t*N*ZD + idx, pm, f);
      float s1 = sd + 1e-10f, s2 = ps + 1e-10f;
      float dm = mean - pm;
      el += 2.f*(logf(s2) - logf(s1)) - (s1*s1 + dm*dm)/(s2*s2) + 1.f;
    }
  }
  __syncthreads();
  sm.red[tid] = el; __syncthreads();
  for (int o = 128; o > 0; o >>= 1){ if (tid < o) sm.red[tid] += sm.red[tid+o]; __syncthreads(); }
  if (tid == 0) atomicAdd(p.scal + 4, sm.red[0] * (0.5f/((float)N*(float)ZD)));
}

__global__ __launch_bounds__(256) void phiz_k(KP p, int t){   // grid 256
  __shared__ SMem sm;
  int gb = blockIdx.x, tid = threadIdx.x, f = *p.dflag;
  int colblk = gb & 3, rowblk = gb >> 2;
  mfma_tile(sm, tid, f, p.zbf, 2, ZD, nullptr, 0, 0, ZD, ZD,
            p.phi_z_w, HD, colblk*64, p.phi_z_b, 1, p.Tb2, HD, rowblk*64, colblk*64);
}

// gru-x GEMM (0-767) + dec tiles, one per block (768-4863)
__global__ __launch_bounds__(256) void grux_dec_k(KP p, int t){   // grid 4864
  __shared__ SMem sm;
  int gb = blockIdx.x, tid = threadIdx.x, f = *p.dflag;
  if (gb < 768){
    const bf16* phiX = p.phiXa + (size_t)t*N*HD;
    int colblk = gb % 12, rowblk = gb / 12;
    int grp = colblk >> 2, c4 = colblk & 3;
    const void* W = (grp == 0) ? p.gxz : ((grp == 1) ? p.gxr : p.gxh);
    mfma_tile(sm, tid, f, phiX, 2, HD, p.Tb2, 2, HD, 256, 512,
              W, HD, c4*64, nullptr, 0, p.Gsx, 768, rowblk*64, colblk*64);
  } else {
    dec_tile1(p, sm, tid, t, gb - 768, f);
  }
}

__global__ __launch_bounds__(256) void zr_k(KP p, int t){   // grid 1024
  int gb = blockIdx.x, tid = threadIdx.x;
  const int* offs_t = p.offs + t*(N+1);
  const int* srcs_t = p.srcs + (size_t)t*E;
  const float* en_t = p.enorm + (size_t)t*E;
  const float* dv_t = p.dinv + t*N;
  int g4 = tid >> 6, lane = tid & 63;
  int n = gb*4 + g4, c = lane*8;
  int e0 = offs_t[n], e1 = offs_t[n+1];
  float d2 = dv_t[n]*dv_t[n];
  float acc[8], v1[8], v2[8];
  ld8b(p.Gsx + (size_t)n*768 + c, v1);
  ld8b(p.Gs1 + 512 + (size_t)n*1024 + c, v2);
  #pragma unroll
  for (int j = 0; j < 8; j++) acc[j] = d2 * (v1[j] + v2[j]);
  for (int e = e0; e < e1; e++){
    int s = srcs_t[e] & (N-1);
    float nm = en_t[e];
    ld8b(p.Gsx + (size_t)s*768 + c, v1);
    ld8b(p.Gs1 + 512 + (size_t)s*1024 + c, v2);
    #pragma unroll
    for (int j = 0; j < 8; j++) acc[j] += nm * (v1[j] + v2[j]);
  }
  if (c < 256){
    size_t base = (size_t)n*HD + c;
    float4 o0, o1;
    o0.x = sigm(acc[0]); o0.y = sigm(acc[1]); o0.z = sigm(acc[2]); o0.w = sigm(acc[3]);
    o1.x = sigm(acc[4]); o1.y = sigm(acc[5]); o1.z = sigm(acc[6]); o1.w = sigm(acc[7]);
    *(float4*)(p.z_g + base) = o0;
    *(float4*)(p.z_g + base + 4) = o1;
  } else {
    size_t base = (size_t)n*HD + (c - 256);
    float r[8];
    #pragma unroll
    for (int j = 0; j < 8; j++) r[j] = sigm(acc[j]) * p.h_prev[base+j];
    uint4 o; o.x = pack2(r[0],r[1]); o.y = pack2(r[2],r[3]);
    o.z = pack2(r[4],r[5]); o.w = pack2(r[6],r[7]);
    *(uint4*)(p.Tb1 + base) = o;
  }
}

__global__ __launch_bounds__(256) void hh_k(KP p, int t){   // grid 256
  __shared__ SMem sm;
  int gb = blockIdx.x, tid = threadIdx.x, f = *p.dflag;
  int colblk = gb & 3, rowblk = gb >> 2;
  mfma_tile(sm, tid, f, p.Tb1, 2, HD, nullptr, 0, 0, 256, 256,
            p.ghh, HD, colblk*64, nullptr, 0, p.Gh2, 256, rowblk*64, colblk*64);
}

__global__ __launch_bounds__(256) void hagg_k(KP p, int t){   // grid 512
  int gb = blockIdx.x, tid = threadIdx.x, f = *p.dflag;
  const int* offs_t = p.offs + t*(N+1);
  const int* srcs_t = p.srcs + (size_t)t*E;
  const float* en_t = p.enorm + (size_t)t*E;
  const float* dv_t = p.dinv + t*N;
  int g8 = tid >> 5, l = tid & 31;
  int n = gb*8 + g8, c = l*8;
  int e0 = offs_t[n], e1 = offs_t[n+1];
  float d2 = dv_t[n]*dv_t[n];
  float acc[8], v1[8], v2[8];
  ld8b(p.Gsx + 512 + (size_t)n*768 + c, v1);
  ld8b(p.Gh2 + (size_t)n*256 + c, v2);
  #pragma unroll
  for (int j = 0; j < 8; j++) acc[j] = d2 * (v1[j] + v2[j]);
  for (int e = e0; e < e1; e++){
    int s = srcs_t[e] & (N-1);
    float nm = en_t[e];
    ld8b(p.Gsx + 512 + (size_t)s*768 + c, v1);
    ld8b(p.Gh2 + (size_t)s*256 + c, v2);
    #pragma unroll
    for (int j = 0; j < 8; j++) acc[j] += nm * (v1[j] + v2[j]);
  }
  size_t base = (size_t)n*HD + c;
  #pragma unroll
  for (int j = 0; j < 8; j++){
    float z = p.z_g[base+j];
    float hv = p.h_prev[base+j];
    float nv = z*hv + (1.f - z)*tanhf(acc[j]);
    p.h_prev[base+j] = nv;
    p.h_bf[base+j] = f2b(nv);
    if (t == T_STEPS-1) stO(p.out, OUT_H + base + j, nv, f);
  }
}

__global__ void fin_k(KP p){
  if (threadIdx.x == 0){
    int f = *p.dflag;
    const float NNf = 16777216.f;
    float nll = 0.f;
    for (int t = 0; t < T_STEPS; t++){
      float ts = p.scal[8+t], P = p.scal[12+t], Q = p.scal[16+t];
      float posw = (NNf - ts)/ts;
      nll += (posw*P + Q) * 0.5f/(NNf - ts);
    }
    stO(p.out, 0, p.scal[4], f);
    stO(p.out, 1, nll, f);
  }
}

// ---------------- host ----------------
extern "C" void kernel_launch(void* const* d_in, const int* in_sizes, int n_in,
                              void* d_out, int out_size, void* d_ws, size_t ws_size,
                              hipStream_t stream){
  KP P;
  P.x = d_in[0];  P.ei = (const int*)d_in[1];  P.adj = d_in[2];  P.eps = d_in[3];  P.h0 = d_in[4];
  P.phi_x_w = d_in[5];  P.phi_x_b = d_in[6];  P.phi_z_w = d_in[7];  P.phi_z_b = d_in[8];
  P.enc_w = d_in[9];  P.enc_b = d_in[10];
  P.enc_mean_w = d_in[11];  P.enc_mean_b = d_in[12];
  P.enc_std_w = d_in[13];   P.enc_std_b = d_in[14];
  P.prior_w = d_in[15];  P.prior_b = d_in[16];
  P.prior_mean_w = d_in[17];  P.prior_mean_b = d_in[18];
  P.prior_std_w = d_in[19];   P.prior_std_b = d_in[20];
  P.gxz = d_in[21];  P.ghz = d_in[22];  P.gxr = d_in[23];
  P.ghr = d_in[24];  P.gxh = d_in[25];  P.ghh = d_in[26];
  P.out = d_out;

  char* wp = (char*)d_ws;
  auto alloc = [&](size_t bytes){ void* q = (void*)wp; wp += (bytes + 255) & ~(size_t)255; return q; };
  P.scal  = (float*)alloc(64*sizeof(float));
  P.dflag = (int*)  alloc(256);
  P.dinv  = (float*)alloc((size_t)T_STEPS*N*4);
  P.offs  = (int*)  alloc((size_t)T_STEPS*(N+1)*4);
  P.srcs  = (int*)  alloc((size_t)T_STEPS*E*4);
  P.enorm = (float*)alloc((size_t)T_STEPS*E*4);
  P.deg   = (int*)  alloc((size_t)T_STEPS*N*4);
  P.h_prev= (float*)alloc((size_t)N*HD*4);
  P.h_bf  = (bf16*) alloc((size_t)N*HD*2);
  P.phiXa = (bf16*) alloc((size_t)T_STEPS*N*HD*2);
  P.Tb1   = (bf16*) alloc((size_t)N*HD*2);
  P.Tb2   = (bf16*) alloc((size_t)N*HD*2);
  P.zbf   = (bf16*) alloc((size_t)N*ZD*2);
  P.z_g   = (float*)alloc((size_t)N*HD*4);
  P.Gs1   = (bf16*) alloc((size_t)N*1024*2);
  P.Gsx   = (bf16*) alloc((size_t)N*768*2);
  P.Gms   = (bf16*) alloc((size_t)N*256*2);
  P.Gh2   = (bf16*) alloc((size_t)N*256*2);

  setup0_k<<<66,256,0,stream>>>(P);
  count_deg_k<<<1024,256,0,stream>>>(P);
  setup2_k<<<1024,256,0,stream>>>(P);
  scatter_k<<<1024,256,0,stream>>>(P);
  for (int t = 0; t < T_STEPS; t++){
    g1_k<<<1024,256,0,stream>>>(P, t);
    encagg_pms_k<<<640,256,0,stream>>>(P, t);
    encms_k<<<128,256,0,stream>>>(P, t);
    msaggpost_k<<<256,256,0,stream>>>(P, t);
    phiz_k<<<256,256,0,stream>>>(P, t);
    grux_dec_k<<<4864,256,0,stream>>>(P, t);
    zr_k<<<1024,256,0,stream>>>(P, t);
    hh_k<<<256,256,0,stream>>>(P, t);
    hagg_k<<<512,256,0,stream>>>(P, t);
  }
  fin_k<<<1,64,0,stream>>>(P);
}